// Round 5
// baseline (405.775 us; speedup 1.0000x reference)
//
#include <hip/hip_runtime.h>

// PRNNCell: B=64, I=512, H=1024, D=1536
//   x = concat(inputs, hidden)                       (B, D)
//   new_hidden = tanh(einsum('bd,bhd->bh', x, wih) + bih)
//   new_wih = wih + y*x*Wa + x*Wb + y*Wc + Wd        (y = new_hidden[b,h])
//   (dop in the reference is dead code -> skipped)
//
// R5 = R3 structure (minimal register state, x re-read in phase 2 from L1/L2)
// + fast_tanh + __launch_bounds__(512,8) to force VGPR<=64 so all 8 waves/SIMD
// (32 waves/CU, 4 blocks/CU, entire 1024-block grid) are co-resident.
// One block per h: Wa..d[h,:] staged once into 24 KB LDS; wih row streamed
// from HBM exactly once (nontemporal), updated, streamed back (nontemporal).

#define BB 64
#define II 512
#define HH 1024
#define DD 1536
#define NF4 (DD / 4)          // 384 vec4 per row
#define THREADS 512
#define PER_WAVE (BB / 8)     // 8 rows per wave

typedef float f4 __attribute__((ext_vector_type(4)));

__device__ __forceinline__ float fast_tanh(float x) {
    // exp overflow -> inf -> 2/inf = 0 -> y=1; underflow -> e=0 -> y=-1.
    const float e = __expf(2.0f * x);
    return 1.0f - 2.0f / (1.0f + e);
}

__global__ __launch_bounds__(THREADS, 8) void prnn_fused(
    const float* __restrict__ inputs,   // B x I
    const float* __restrict__ hidden,   // B x H
    const float* __restrict__ wih,      // B x H x D
    const float* __restrict__ Wa,       // H x D
    const float* __restrict__ Wb,
    const float* __restrict__ Wc,
    const float* __restrict__ Wd,
    const float* __restrict__ bih,      // H
    float* __restrict__ out_h,          // B x H
    float* __restrict__ out_w)          // B x H x D
{
    __shared__ f4 sA[NF4], sB[NF4], sC[NF4], sD[NF4];   // 24 KB

    const int h    = blockIdx.x;
    const int tid  = threadIdx.x;
    const int lane = tid & 63;
    const int wid  = tid >> 6;

    if (tid < NF4) {
        sA[tid] = ((const f4*)(Wa + (size_t)h * DD))[tid];
        sB[tid] = ((const f4*)(Wb + (size_t)h * DD))[tid];
        sC[tid] = ((const f4*)(Wc + (size_t)h * DD))[tid];
        sD[tid] = ((const f4*)(Wd + (size_t)h * DD))[tid];
    }
    const float bh = bih[h];
    __syncthreads();

    for (int i = 0; i < PER_WAVE; ++i) {
        const int b    = wid * PER_WAVE + i;            // wave-uniform
        const size_t r = (size_t)b * HH + h;
        const f4* __restrict__ wrow = (const f4*)(wih + r * DD);
        const f4* __restrict__ xin  = (const f4*)(inputs + (size_t)b * II);
        const f4* __restrict__ xhi  = (const f4*)(hidden + (size_t)b * HH);

        // Phase 1: stream wih row into regs, dot with x (x not kept live).
        f4 wv[6];
        float dot = 0.f;
#pragma unroll
        for (int k = 0; k < 6; ++k) {
            const int j = lane + 64 * k;                // 0..383
            wv[k] = __builtin_nontemporal_load(&wrow[j]);
            const f4 xk = (k < 2) ? xin[j] : xhi[j - 128];
            dot += xk.x * wv[k].x + xk.y * wv[k].y
                 + xk.z * wv[k].z + xk.w * wv[k].w;
        }
#pragma unroll
        for (int off = 32; off >= 1; off >>= 1)
            dot += __shfl_xor(dot, off, 64);
        const float y = fast_tanh(dot + bh);
        if (lane == 0) out_h[r] = y;

        // Phase 2: update from LDS + regs; x re-read (L1/L2-hot).
        f4* __restrict__ orow = (f4*)(out_w + r * DD);
#pragma unroll
        for (int k = 0; k < 6; ++k) {
            const int j = lane + 64 * k;
            const f4 xk = (k < 2) ? xin[j] : xhi[j - 128];
            const f4 a  = sA[j];
            const f4 b2 = sB[j];
            const f4 c  = sC[j];
            const f4 d  = sD[j];
            f4 o;
            o.x = wv[k].x + xk.x * fmaf(y, a.x, b2.x) + fmaf(y, c.x, d.x);
            o.y = wv[k].y + xk.y * fmaf(y, a.y, b2.y) + fmaf(y, c.y, d.y);
            o.z = wv[k].z + xk.z * fmaf(y, a.z, b2.z) + fmaf(y, c.z, d.z);
            o.w = wv[k].w + xk.w * fmaf(y, a.w, b2.w) + fmaf(y, c.w, d.w);
            __builtin_nontemporal_store(o, &orow[j]);
        }
    }
}

extern "C" void kernel_launch(void* const* d_in, const int* in_sizes, int n_in,
                              void* d_out, int out_size, void* d_ws, size_t ws_size,
                              hipStream_t stream) {
    const float* inputs = (const float*)d_in[0];
    const float* hidden = (const float*)d_in[1];
    const float* wih    = (const float*)d_in[2];
    const float* Wa     = (const float*)d_in[3];
    const float* Wb     = (const float*)d_in[4];
    const float* Wc     = (const float*)d_in[5];
    const float* Wd     = (const float*)d_in[6];
    const float* bih    = (const float*)d_in[7];
    // d_in[8] = W_dop, d_in[9] = b_dop: dead code in the reference, unused.

    float* out   = (float*)d_out;
    float* out_h = out;                    // B*H floats
    float* out_w = out + (size_t)BB * HH;  // B*H*D floats

    dim3 grid(HH), block(THREADS);
    prnn_fused<<<grid, block, 0, stream>>>(inputs, hidden, wih, Wa, Wb, Wc, Wd,
                                           bih, out_h, out_w);
}

// Round 6
// 170.301 us; speedup vs baseline: 2.3827x; 2.3827x over previous
//
#include <hip/hip_runtime.h>

// PRNNCell: B=64, I=512, H=1024, D=1536
//   x = concat(inputs, hidden)                       (B, D)
//   new_hidden = tanh(einsum('bd,bhd->bh', x, wih) + bih)
//   new_wih = wih + y*x*Wa + x*Wb + y*Wc + Wd        (y = new_hidden[b,h])
//   (dop in the reference is dead code -> skipped)
//
// R6 = R3 (162.9 us known-good: one block per h, Wa..d in 24 KB LDS, wih
// streamed NT once, x re-read in phase 2 from cache, natural VGPR ~40-64)
//   + XCD-aware h swizzle: XCD x owns contiguous h in [128x, 128x+128), so
//     each XCD's HBM miss stream covers contiguous 768 KB spans of wih per b.
//   + Wa..d staged by all 512 threads (3 vec4 each) instead of 384.
// NOTE: launch_bounds min-waves=8 (R5) forced VGPR=32 and spilled wv[6] to
// scratch (+700 MB HBM traffic, 443 us). Do NOT re-add it.

#define BB 64
#define II 512
#define HH 1024
#define DD 1536
#define NF4 (DD / 4)          // 384 vec4 per row
#define THREADS 512
#define PER_WAVE (BB / 8)     // 8 rows per wave

typedef float f4 __attribute__((ext_vector_type(4)));

__device__ __forceinline__ float fast_tanh(float x) {
    // exp overflow -> inf -> 2/inf = 0 -> y=1; underflow -> e=0 -> y=-1.
    const float e = __expf(2.0f * x);
    return 1.0f - 2.0f / (1.0f + e);
}

__global__ __launch_bounds__(THREADS) void prnn_fused(
    const float* __restrict__ inputs,   // B x I
    const float* __restrict__ hidden,   // B x H
    const float* __restrict__ wih,      // B x H x D
    const float* __restrict__ Wa,       // H x D
    const float* __restrict__ Wb,
    const float* __restrict__ Wc,
    const float* __restrict__ Wd,
    const float* __restrict__ bih,      // H
    float* __restrict__ out_h,          // B x H
    float* __restrict__ out_w)          // B x H x D
{
    __shared__ f4 sW[4 * NF4];          // A|B|C|D, 24 KB

    // XCD-aware swizzle: grid 1024 = 8 XCDs x 128 contiguous h each.
    const int h    = (blockIdx.x & 7) * 128 + (blockIdx.x >> 3);
    const int tid  = threadIdx.x;
    const int lane = tid & 63;
    const int wid  = tid >> 6;

    {   // stage Wa..d[h,:]: 4*384 = 1536 vec4 across 512 threads, 3 each.
        const float* base[4] = {Wa, Wb, Wc, Wd};
#pragma unroll
        for (int t = 0; t < 3; ++t) {
            const int s = tid + t * THREADS;            // 0..1535
            const int arr = s / NF4;                    // which of A..D
            const int idx = s - arr * NF4;
            sW[s] = ((const f4*)(base[arr] + (size_t)h * DD))[idx];
        }
    }
    const float bh = bih[h];
    __syncthreads();

    const f4* __restrict__ sA = sW;
    const f4* __restrict__ sB = sW + NF4;
    const f4* __restrict__ sC = sW + 2 * NF4;
    const f4* __restrict__ sD = sW + 3 * NF4;

    for (int i = 0; i < PER_WAVE; ++i) {
        const int b    = wid * PER_WAVE + i;            // wave-uniform
        const size_t r = (size_t)b * HH + h;
        const f4* __restrict__ wrow = (const f4*)(wih + r * DD);
        const f4* __restrict__ xin  = (const f4*)(inputs + (size_t)b * II);
        const f4* __restrict__ xhi  = (const f4*)(hidden + (size_t)b * HH);

        // Phase 1: stream wih row into regs, dot with x (x not kept live).
        f4 wv[6];
        float dot = 0.f;
#pragma unroll
        for (int k = 0; k < 6; ++k) {
            const int j = lane + 64 * k;                // 0..383
            wv[k] = __builtin_nontemporal_load(&wrow[j]);
            const f4 xk = (k < 2) ? xin[j] : xhi[j - 128];
            dot += xk.x * wv[k].x + xk.y * wv[k].y
                 + xk.z * wv[k].z + xk.w * wv[k].w;
        }
#pragma unroll
        for (int off = 32; off >= 1; off >>= 1)
            dot += __shfl_xor(dot, off, 64);
        const float y = fast_tanh(dot + bh);
        if (lane == 0) out_h[r] = y;

        // Phase 2: update from LDS + regs; x re-read (L1/L2-hot).
        f4* __restrict__ orow = (f4*)(out_w + r * DD);
#pragma unroll
        for (int k = 0; k < 6; ++k) {
            const int j = lane + 64 * k;
            const f4 xk = (k < 2) ? xin[j] : xhi[j - 128];
            const f4 a  = sA[j];
            const f4 b2 = sB[j];
            const f4 c  = sC[j];
            const f4 d  = sD[j];
            f4 o;
            o.x = wv[k].x + xk.x * fmaf(y, a.x, b2.x) + fmaf(y, c.x, d.x);
            o.y = wv[k].y + xk.y * fmaf(y, a.y, b2.y) + fmaf(y, c.y, d.y);
            o.z = wv[k].z + xk.z * fmaf(y, a.z, b2.z) + fmaf(y, c.z, d.z);
            o.w = wv[k].w + xk.w * fmaf(y, a.w, b2.w) + fmaf(y, c.w, d.w);
            __builtin_nontemporal_store(o, &orow[j]);
        }
    }
}

extern "C" void kernel_launch(void* const* d_in, const int* in_sizes, int n_in,
                              void* d_out, int out_size, void* d_ws, size_t ws_size,
                              hipStream_t stream) {
    const float* inputs = (const float*)d_in[0];
    const float* hidden = (const float*)d_in[1];
    const float* wih    = (const float*)d_in[2];
    const float* Wa     = (const float*)d_in[3];
    const float* Wb     = (const float*)d_in[4];
    const float* Wc     = (const float*)d_in[5];
    const float* Wd     = (const float*)d_in[6];
    const float* bih    = (const float*)d_in[7];
    // d_in[8] = W_dop, d_in[9] = b_dop: dead code in the reference, unused.

    float* out   = (float*)d_out;
    float* out_h = out;                    // B*H floats
    float* out_w = out + (size_t)BB * HH;  // B*H*D floats

    dim3 grid(HH), block(THREADS);
    prnn_fused<<<grid, block, 0, stream>>>(inputs, hidden, wih, Wa, Wb, Wc, Wd,
                                           bih, out_h, out_w);
}